// Round 4
// baseline (2888.302 us; speedup 1.0000x reference)
//
#include <hip/hip_runtime.h>
#include <hip/hip_bf16.h>

// ---------------------------------------------------------------------------
// NVFP4 18-layer MLP.  B=256, HID=2048, MLP=8192, 18 layers.
// Per layer: gateup kernel (gate+up GEMM fused, SwiGLU epilogue -> h bf16),
//            down kernel (split-K=8, f32 partials), reduce kernel (sum -> a).
// Weights: packed [N][K/2] bytes stored one-byte-per-int32; dequant direct to
// MFMA B-fragments (no LDS for weights).  Activations staged in padded LDS.
// ws layout: a bf16 1MB @0 | h bf16 4MB @1MB | partials f32 16MB @5MB (21MB).
// ---------------------------------------------------------------------------

typedef __attribute__((ext_vector_type(4))) float f32x4;
typedef __attribute__((ext_vector_type(8))) short bf16x8;
typedef __attribute__((ext_vector_type(4))) int   i32x4;

#if defined(__has_builtin)
#if __has_builtin(__builtin_amdgcn_cvt_scalef32_pk_bf16_fp4)
#define HAVE_CVT_FP4 1
#endif
#endif
#ifndef HAVE_CVT_FP4
#define HAVE_CVT_FP4 0
#endif

__device__ __forceinline__ unsigned pk_bf16(float lo, float hi) {
  unsigned r;
  asm("v_cvt_pk_bf16_f32 %0, %1, %2" : "=v"(r) : "v"(lo), "v"(hi));
  return r;
}

// Fallback decode: 4 nibbles (one per byte of `nib`) -> 4 scaled f32.
// bf16 magnitude tables for idx 0..7 = {0,.5,1,1.5,2,3,4,6}:
//   high byte: 00 3F 3F 3F 40 40 40 40 ; low byte: 00 00 80 C0 00 40 80 C0
__device__ __forceinline__ void dec4(unsigned nib, float s, float o[4]) {
  unsigned idx = nib & 0x07070707u;
  unsigned sgn = (nib & 0x08080808u) << 4;            // 0x80 per byte if negative
  unsigned hB = __builtin_amdgcn_perm(0x40404040u, 0x3F3F3F00u, idx) | sgn;
  unsigned lB = __builtin_amdgcn_perm(0xC0804000u, 0xC0800000u, idx);
  o[0] = __uint_as_float(__builtin_amdgcn_perm(hB, lB, 0x04000C0Cu)) * s;
  o[1] = __uint_as_float(__builtin_amdgcn_perm(hB, lB, 0x05010C0Cu)) * s;
  o[2] = __uint_as_float(__builtin_amdgcn_perm(hB, lB, 0x06020C0Cu)) * s;
  o[3] = __uint_as_float(__builtin_amdgcn_perm(hB, lB, 0x07030C0Cu)) * s;
}

// 4 packed-byte words (one byte each, 2 fp4/byte) + f32 scale -> bf16x8 frag.
// Element order: word i -> k = 2i (low nibble), 2i+1 (high nibble).
__device__ __forceinline__ bf16x8 dequant8(i32x4 w, float s) {
#if HAVE_CVT_FP4
  union { bf16x8 v; unsigned u[4]; } r;
  {
    auto t0 = __builtin_amdgcn_cvt_scalef32_pk_bf16_fp4((unsigned)w[0], s, 0);
    auto t1 = __builtin_amdgcn_cvt_scalef32_pk_bf16_fp4((unsigned)w[1], s, 0);
    auto t2 = __builtin_amdgcn_cvt_scalef32_pk_bf16_fp4((unsigned)w[2], s, 0);
    auto t3 = __builtin_amdgcn_cvt_scalef32_pk_bf16_fp4((unsigned)w[3], s, 0);
    __builtin_memcpy(&r.u[0], &t0, 4);
    __builtin_memcpy(&r.u[1], &t1, 4);
    __builtin_memcpy(&r.u[2], &t2, 4);
    __builtin_memcpy(&r.u[3], &t3, 4);
  }
  return r.v;
#else
  unsigned P = (unsigned)(w[0] & 0xFF) | ((unsigned)(w[1] & 0xFF) << 8) |
               ((unsigned)(w[2] & 0xFF) << 16) | ((unsigned)(w[3] & 0xFF) << 24);
  float e[4], o[4];
  dec4(P & 0x0F0F0F0Fu, s, e);          // even k
  dec4((P >> 4) & 0x0F0F0F0Fu, s, o);   // odd k
  union { bf16x8 v; unsigned u[4]; } r;
  r.u[0] = pk_bf16(e[0], o[0]);
  r.u[1] = pk_bf16(e[1], o[1]);
  r.u[2] = pk_bf16(e[2], o[2]);
  r.u[3] = pk_bf16(e[3], o[3]);
  return r.v;
#endif
}

__device__ __forceinline__ unsigned short bf16b(float f) {
  __hip_bfloat16 h = __float2bfloat16(f);
  unsigned short u; __builtin_memcpy(&u, &h, 2); return u;
}

#define LDS_STRIDE 72   // shorts per row: 64 data + 8 pad (144B: 2-way banks on read)

// gate+up GEMM.  Block: 32 cols, 8 waves = 4 M-halves x 2 col-halves.
// Wave: 16 cols of BOTH gate and up, 64 rows.  grid = 8192/32 = 256.
__global__ __launch_bounds__(512, 2) void k_gateup(
    const unsigned short* __restrict__ A,   // [256][2048] bf16
    const int* __restrict__ gW, const float* __restrict__ gS,
    const int* __restrict__ uW, const float* __restrict__ uS,
    unsigned short* __restrict__ H)         // [256][8192] bf16
{
  __shared__ short lds[2][256 * LDS_STRIDE];
  const int tid  = threadIdx.x;
  const int lane = tid & 63;
  const int w    = tid >> 6;
  const int mh   = w & 3;                 // rows mh*64 .. +64
  const int ch   = w >> 2;                // col half
  const int n    = blockIdx.x * 32 + ch * 16 + (lane & 15);
  const int kq   = lane >> 4;             // 0..3

  const int sq = tid & 7;                 // staging k-part (8 bf16 each)
  const int sr = tid >> 3;                // staging row 0..63 (+64*j)

  const i32x4* gW4 = (const i32x4*)gW;
  const i32x4* uW4 = (const i32x4*)uW;

  f32x4 accG[4] = {};
  f32x4 accU[4] = {};

  // stage chunk 0 (BK=64)
#pragma unroll
  for (int j = 0; j < 4; ++j) {
    int r = sr + 64 * j;
    i32x4 v = *(const i32x4*)(A + r * 2048 + sq * 8);
    *(i32x4*)&lds[0][r * LDS_STRIDE + sq * 8] = v;
  }
  __syncthreads();

  // preload weights for chunk 0 (ksteps 0,1)
  i32x4 wg0 = gW4[n * 256 + 0 + kq];
  i32x4 wg1 = gW4[n * 256 + 4 + kq];
  i32x4 wu0 = uW4[n * 256 + 0 + kq];
  i32x4 wu1 = uW4[n * 256 + 4 + kq];
  float sg0 = gS[n * 64 + 0], sg1 = gS[n * 64 + 1];
  float su0 = uS[n * 64 + 0], su1 = uS[n * 64 + 1];

  for (int c = 0; c < 32; ++c) {
    const int cur = c & 1;
    const bool more = (c < 31);
    // prefetch next A chunk (global -> regs)
    i32x4 pre[4];
    if (more) {
      int kb = (c + 1) * 64;
#pragma unroll
      for (int j = 0; j < 4; ++j) {
        int r = sr + 64 * j;
        pre[j] = *(const i32x4*)(A + r * 2048 + kb + sq * 8);
      }
    }
    // prefetch next weights
    i32x4 wg0n, wg1n, wu0n, wu1n; float sg0n, sg1n, su0n, su1n;
    if (more) {
      int ks = (c + 1) * 2;
      wg0n = gW4[n * 256 + ks * 4 + kq];
      wg1n = gW4[n * 256 + ks * 4 + 4 + kq];
      wu0n = uW4[n * 256 + ks * 4 + kq];
      wu1n = uW4[n * 256 + ks * 4 + 4 + kq];
      sg0n = gS[n * 64 + ks]; sg1n = gS[n * 64 + ks + 1];
      su0n = uS[n * 64 + ks]; su1n = uS[n * 64 + ks + 1];
    }
    // compute chunk c
    bf16x8 bg0 = dequant8(wg0, sg0);
    bf16x8 bu0 = dequant8(wu0, su0);
    bf16x8 bg1 = dequant8(wg1, sg1);
    bf16x8 bu1 = dequant8(wu1, su1);
    const short* base = &lds[cur][0];
#pragma unroll
    for (int ms = 0; ms < 4; ++ms) {
      int row = mh * 64 + ms * 16 + (lane & 15);
      bf16x8 a0 = *(const bf16x8*)(base + row * LDS_STRIDE + kq * 8);
      bf16x8 a1 = *(const bf16x8*)(base + row * LDS_STRIDE + 32 + kq * 8);
      accG[ms] = __builtin_amdgcn_mfma_f32_16x16x32_bf16(a0, bg0, accG[ms], 0, 0, 0);
      accU[ms] = __builtin_amdgcn_mfma_f32_16x16x32_bf16(a0, bu0, accU[ms], 0, 0, 0);
      accG[ms] = __builtin_amdgcn_mfma_f32_16x16x32_bf16(a1, bg1, accG[ms], 0, 0, 0);
      accU[ms] = __builtin_amdgcn_mfma_f32_16x16x32_bf16(a1, bu1, accU[ms], 0, 0, 0);
    }
    __syncthreads();
    if (more) {
#pragma unroll
      for (int j = 0; j < 4; ++j) {
        int r = sr + 64 * j;
        *(i32x4*)&lds[cur ^ 1][r * LDS_STRIDE + sq * 8] = pre[j];
      }
    }
    __syncthreads();
    wg0 = wg0n; wg1 = wg1n; wu0 = wu0n; wu1 = wu1n;
    sg0 = sg0n; sg1 = sg1n; su0 = su0n; su1 = su1n;
  }

  // epilogue: h = silu(g)*u, bf16, m-major
#pragma unroll
  for (int ms = 0; ms < 4; ++ms) {
#pragma unroll
    for (int i = 0; i < 4; ++i) {
      int m = mh * 64 + ms * 16 + kq * 4 + i;
      float g = accG[ms][i];
      float u = accU[ms][i];
      float h = g / (1.0f + __expf(-g)) * u;
      H[m * 8192 + n] = bf16b(h);
    }
  }
}

// down GEMM, split-K=8.  Block: 64 cols x K-range 1024.  grid = 32*8 = 256.
// Wave: 32 cols (2 stripes), 64 rows.
__global__ __launch_bounds__(512, 2) void k_down(
    const unsigned short* __restrict__ Hb,  // [256][8192] bf16
    const int* __restrict__ dW, const float* __restrict__ dS,
    float* __restrict__ part)               // [8][256][2048] f32
{
  __shared__ short lds[2][256 * LDS_STRIDE];
  const int tid  = threadIdx.x;
  const int lane = tid & 63;
  const int w    = tid >> 6;
  const int mh   = w & 3;
  const int ch   = w >> 2;
  const int cb   = blockIdx.x & 31;
  const int s    = blockIdx.x >> 5;          // split 0..7
  const int nb   = cb * 64 + ch * 32;
  const int n0   = nb + (lane & 15);
  const int n1   = nb + 16 + (lane & 15);
  const int kq   = lane >> 4;

  const int sq = tid & 7;
  const int sr = tid >> 3;

  const i32x4* dW4 = (const i32x4*)dW;

  f32x4 acc0[4] = {};
  f32x4 acc1[4] = {};

  const int kb0 = s * 1024;
  const int ks0 = s * 32;

#pragma unroll
  for (int j = 0; j < 4; ++j) {
    int r = sr + 64 * j;
    i32x4 v = *(const i32x4*)(Hb + r * 8192 + kb0 + sq * 8);
    *(i32x4*)&lds[0][r * LDS_STRIDE + sq * 8] = v;
  }
  __syncthreads();

  i32x4 w00 = dW4[n0 * 1024 + ks0 * 4 + kq];
  i32x4 w01 = dW4[n0 * 1024 + ks0 * 4 + 4 + kq];
  i32x4 w10 = dW4[n1 * 1024 + ks0 * 4 + kq];
  i32x4 w11 = dW4[n1 * 1024 + ks0 * 4 + 4 + kq];
  float s00 = dS[n0 * 256 + ks0], s01 = dS[n0 * 256 + ks0 + 1];
  float s10 = dS[n1 * 256 + ks0], s11 = dS[n1 * 256 + ks0 + 1];

  for (int c = 0; c < 16; ++c) {
    const int cur = c & 1;
    const bool more = (c < 15);
    i32x4 pre[4];
    if (more) {
      int kb = kb0 + (c + 1) * 64;
#pragma unroll
      for (int j = 0; j < 4; ++j) {
        int r = sr + 64 * j;
        pre[j] = *(const i32x4*)(Hb + r * 8192 + kb + sq * 8);
      }
    }
    i32x4 w00n, w01n, w10n, w11n; float s00n, s01n, s10n, s11n;
    if (more) {
      int ks = ks0 + (c + 1) * 2;
      w00n = dW4[n0 * 1024 + ks * 4 + kq];
      w01n = dW4[n0 * 1024 + ks * 4 + 4 + kq];
      w10n = dW4[n1 * 1024 + ks * 4 + kq];
      w11n = dW4[n1 * 1024 + ks * 4 + 4 + kq];
      s00n = dS[n0 * 256 + ks]; s01n = dS[n0 * 256 + ks + 1];
      s10n = dS[n1 * 256 + ks]; s11n = dS[n1 * 256 + ks + 1];
    }
    bf16x8 b00 = dequant8(w00, s00);
    bf16x8 b01 = dequant8(w01, s01);
    bf16x8 b10 = dequant8(w10, s10);
    bf16x8 b11 = dequant8(w11, s11);
    const short* base = &lds[cur][0];
#pragma unroll
    for (int ms = 0; ms < 4; ++ms) {
      int row = mh * 64 + ms * 16 + (lane & 15);
      bf16x8 a0 = *(const bf16x8*)(base + row * LDS_STRIDE + kq * 8);
      bf16x8 a1 = *(const bf16x8*)(base + row * LDS_STRIDE + 32 + kq * 8);
      acc0[ms] = __builtin_amdgcn_mfma_f32_16x16x32_bf16(a0, b00, acc0[ms], 0, 0, 0);
      acc1[ms] = __builtin_amdgcn_mfma_f32_16x16x32_bf16(a0, b10, acc1[ms], 0, 0, 0);
      acc0[ms] = __builtin_amdgcn_mfma_f32_16x16x32_bf16(a1, b01, acc0[ms], 0, 0, 0);
      acc1[ms] = __builtin_amdgcn_mfma_f32_16x16x32_bf16(a1, b11, acc1[ms], 0, 0, 0);
    }
    __syncthreads();
    if (more) {
#pragma unroll
      for (int j = 0; j < 4; ++j) {
        int r = sr + 64 * j;
        *(i32x4*)&lds[cur ^ 1][r * LDS_STRIDE + sq * 8] = pre[j];
      }
    }
    __syncthreads();
    w00 = w00n; w01 = w01n; w10 = w10n; w11 = w11n;
    s00 = s00n; s01 = s01n; s10 = s10n; s11 = s11n;
  }

  float* pbase = part + s * (256 * 2048);
#pragma unroll
  for (int ms = 0; ms < 4; ++ms) {
#pragma unroll
    for (int i = 0; i < 4; ++i) {
      int m = mh * 64 + ms * 16 + kq * 4 + i;
      pbase[m * 2048 + n0] = acc0[ms][i];
      pbase[m * 2048 + n1] = acc1[ms][i];
    }
  }
}

// sum 8 split-K partials -> bf16 activation (and f32 final output on last layer)
__global__ void k_reduce(const float* __restrict__ part,
                         unsigned short* __restrict__ aout,
                         float* __restrict__ fout) {
  int i = (blockIdx.x * 256 + threadIdx.x) * 4;
  f32x4 v = *(const f32x4*)(part + i);
#pragma unroll
  for (int p = 1; p < 8; ++p) v += *(const f32x4*)(part + p * 524288 + i);
  uint2 t;
  t.x = pk_bf16(v[0], v[1]);
  t.y = pk_bf16(v[2], v[3]);
  *(uint2*)(aout + i) = t;
  if (fout) *(f32x4*)(fout + i) = v;
}

__global__ void k_cvt(const float* __restrict__ x, unsigned short* __restrict__ a) {
  int i = (blockIdx.x * 256 + threadIdx.x) * 4;
  f32x4 v = *(const f32x4*)(x + i);
  uint2 t;
  t.x = pk_bf16(v[0], v[1]);
  t.y = pk_bf16(v[2], v[3]);
  *(uint2*)(a + i) = t;
}

extern "C" void kernel_launch(void* const* d_in, const int* in_sizes, int n_in,
                              void* d_out, int out_size, void* d_ws, size_t ws_size,
                              hipStream_t stream) {
  const float* x  = (const float*)d_in[0];
  const int*   gW = (const int*)d_in[1];
  const float* gS = (const float*)d_in[2];
  const int*   uW = (const int*)d_in[3];
  const float* uS = (const float*)d_in[4];
  const int*   dW = (const int*)d_in[5];
  const float* dS = (const float*)d_in[6];
  float* out = (float*)d_out;

  char* ws = (char*)d_ws;
  unsigned short* a    = (unsigned short*)ws;               // 1 MB bf16 [256][2048]
  unsigned short* h    = (unsigned short*)(ws + (1 << 20)); // 4 MB bf16 [256][8192]
  float*          part = (float*)(ws + (5 << 20));          // 16 MB f32 [8][256][2048]

  k_cvt<<<512, 256, 0, stream>>>(x, a);
  for (int l = 0; l < 18; ++l) {
    k_gateup<<<256, 512, 0, stream>>>(a,
        gW + (size_t)l * 8388608, gS + (size_t)l * 524288,
        uW + (size_t)l * 8388608, uS + (size_t)l * 524288, h);
    k_down<<<256, 512, 0, stream>>>(h,
        dW + (size_t)l * 8388608, dS + (size_t)l * 524288, part);
    k_reduce<<<512, 256, 0, stream>>>(part, a, (l == 17) ? out : nullptr);
  }
}